// Round 2
// baseline (18153.090 us; speedup 1.0000x reference)
//
#include <hip/hip_runtime.h>
#include <hip/hip_bf16.h>

// ---------------------------------------------------------------------------
// StandardMRALSTM — round 2: dual-dtype (runtime-sniffed) fp32-compute impl.
//   * Mode flag: boundary is uniform(0,1); even-u16 decode in [0,1] => bf16,
//     else fp32. Written to ws[0] by init_kernel; uniform branch per kernel.
//   * Scan: 512 sequential launches (t,k). fp32 h ping-pong for recurrence
//     (exactness for the mean(sg)>0.5 knife-edge), bf16 h history for excite.
//   * Excite: per (b, 4 timesteps) block; Q/R/Wo GEMMs scalar fp32.
// ws layout (float units): [0] mode flag | 64: sgsum[512] | 1024: c[L*B*H]
//   | 132096: hping[2][L*B*H] | 394240: h_hist bf16 [T][L][B][H] (u16)
// total ~33.5 MB
// ---------------------------------------------------------------------------

#define LL 4
#define HH 512
#define TS 128
#define GG 16
#define BB 64
#define FF 64
#define FIVE_H 2560
#define TT 4

typedef unsigned short u16;
typedef unsigned int u32;

#define SG_OFF 64
#define C_OFF  1024
#define HP_OFF (C_OFF + LL * BB * HH)        // 132096
#define HH_OFF (HP_OFF + 2 * LL * BB * HH)   // 394240 (bf16 region starts here)

__device__ __forceinline__ float bf2f(u16 u) { return __uint_as_float(((u32)u) << 16); }
__device__ __forceinline__ float2 bf2x2(u32 u) {
    float2 r;
    r.x = __uint_as_float(u << 16);
    r.y = __uint_as_float(u & 0xFFFF0000u);
    return r;
}
__device__ __forceinline__ u16 f2bf_rne(float f) {
    u32 x = __float_as_uint(f);
    return (u16)((x + 0x7FFFu + ((x >> 16) & 1u)) >> 16);
}

template <bool BF>
__device__ __forceinline__ float ldv(const void* p, size_t i) {
    return BF ? bf2f(((const u16*)p)[i]) : ((const float*)p)[i];
}
template <bool BF>
__device__ __forceinline__ const void* elem(const void* p, size_t off) {
    return BF ? (const void*)((const u16*)p + off) : (const void*)((const float*)p + off);
}

template <bool BF>
__device__ __forceinline__ float dot128(const void* rowv, const float* h, int c0) {
    float acc = 0.f;
    if (BF) {
        const uint4* p = (const uint4*)((const u16*)rowv + c0);
        const float4* hv = (const float4*)(h + c0);
#pragma unroll
        for (int it = 0; it < 16; ++it) {
            uint4 q = p[it];
            float4 h0 = hv[2 * it], h1 = hv[2 * it + 1];
            float2 a0 = bf2x2(q.x), a1 = bf2x2(q.y), a2 = bf2x2(q.z), a3 = bf2x2(q.w);
            acc += a0.x * h0.x + a0.y * h0.y + a1.x * h0.z + a1.y * h0.w;
            acc += a2.x * h1.x + a2.y * h1.y + a3.x * h1.z + a3.y * h1.w;
        }
    } else {
        const float4* p = (const float4*)((const float*)rowv + c0);
        const float4* hv = (const float4*)(h + c0);
#pragma unroll
        for (int it = 0; it < 32; ++it) {
            float4 a = p[it], hh = hv[it];
            acc += a.x * hh.x + a.y * hh.y + a.z * hh.z + a.w * hh.w;
        }
    }
    return acc;
}

template <bool BF>
__device__ __forceinline__ float dot4(const void* rowv, const float* xs, int g0) {
    if (BF) {
        uint2 q = *(const uint2*)((const u16*)rowv + g0);
        float2 a0 = bf2x2(q.x), a1 = bf2x2(q.y);
        return a0.x * xs[g0] + a0.y * xs[g0 + 1] + a1.x * xs[g0 + 2] + a1.y * xs[g0 + 3];
    } else {
        float4 a = *(const float4*)((const float*)rowv + g0);
        return a.x * xs[g0] + a.y * xs[g0 + 1] + a.z * xs[g0 + 2] + a.w * xs[g0 + 3];
    }
}

// Zero sgsum + c, and sniff the dtype from boundary's raw u16 stream.
__global__ void init_kernel(const u16* __restrict__ bnd_raw, float* __restrict__ ws) {
    size_t i = (size_t)blockIdx.x * 256 + threadIdx.x;
    if (i < 512) ws[SG_OFF + i] = 0.f;
    if (i < (size_t)LL * BB * HH) ws[C_OFF + i] = 0.f;
    if (blockIdx.x == 0 && threadIdx.x == 0) {
        int bf = 1;
        for (int j = 0; j < 32; ++j) {
            float v = bf2f(bnd_raw[2 * j]);  // bf16 mode: elements 0,2,..; f32 mode: mantissa halves
            if (!(v >= 0.f && v <= 1.f)) bf = 0;
        }
        ((int*)ws)[0] = bf;
    }
}

template <bool BF>
__device__ void step_body(const void* xin, const void* Wm, const void* Zm,
                          const void* Um, const void* Vm, const void* Jm,
                          const void* bbias, const void* bnd,
                          float* ws, float* smem, int t, int k) {
    float* sh_hpk  = smem;            // 512
    float* sh_hpkn = smem + 512;      // 512
    float* sh_hlow = smem + 1024;     // 512
    float* sh_x    = smem + 1536;     // 16
    float* sh_part = smem + 1552;     // 1280
    int*   sh_z    = (int*)(smem + 2832);

    float* c_buf = ws + C_OFF;
    float* sgsum = ws + SG_OFF;
    float* hprev_sl = ws + HP_OFF + (size_t)((t + 1) & 1) * LL * BB * HH;  // slice (t-1)&1
    float* hcur_sl  = ws + HP_OFF + (size_t)(t & 1) * LL * BB * HH;
    u16* hhist = (u16*)(ws + HH_OFF);

    int tid = threadIdx.x;
    int wave = tid >> 6, lane = tid & 63;
    int jt = blockIdx.x & 7, b = blockIdx.x >> 3;   // XCD swizzle on j-tile
    int kn = (k + 1 < LL) ? k + 1 : LL - 1;
    int km = (k > 0) ? k - 1 : 0;

    const float* hp  = hprev_sl + ((size_t)k  * BB + b) * HH;
    const float* hpn = hprev_sl + ((size_t)kn * BB + b) * HH;
    const float* hl  = hcur_sl  + ((size_t)km * BB + b) * HH;
    for (int i = tid; i < HH; i += 256) {
        sh_hpk[i]  = (t > 0) ? hp[i]  : 0.f;
        sh_hpkn[i] = (t > 0) ? hpn[i] : 0.f;
        sh_hlow[i] = (k > 0) ? hl[i]  : 0.f;
    }
    if (tid == 0) {
        int z = 0;
        size_t xbase = ((size_t)b * TS + t) * FF + k * GG;
        for (int g = 0; g < GG; ++g) {
            float v = ldv<BF>(xin, xbase + g);
            bool nn = (v != v);
            sh_x[g] = nn ? 0.f : v;
            z |= nn ? 0 : 1;
        }
        *sh_z = z;
    }
    bool p_hi = (t == 0) ? (ldv<BF>(bnd, (size_t)k * TS) > 0.5f)
                         : (sgsum[(t - 1) * LL + k] > 16384.f);
    bool l_hi = (k == 0) ? (ldv<BF>(bnd, (size_t)t) > 0.5f)
                         : (sgsum[t * LL + (k - 1)] > 16384.f);
    int mcase = p_hi ? (l_hi ? 3 : 2) : (l_hi ? 1 : 4);
    __syncthreads();
    bool zb = (*sh_z != 0);

    int j = jt * 64 + lane;
    int c0 = wave * 128, g0 = wave * 4;
    const void* Wk = elem<BF>(Wm, (size_t)k * FIVE_H * HH);
    const void* Zk = elem<BF>(Zm, (size_t)k * FIVE_H * HH);
    const void* Uk = elem<BF>(Um, (size_t)k * FIVE_H * (HH + GG));
    const void* Vk = elem<BF>(Vm, (size_t)k * FIVE_H * HH);
    const void* Jk = elem<BF>(Jm, (size_t)k * FIVE_H * GG);

    for (int i = 0; i < 5; ++i) {
        size_t r = (size_t)i * HH + j;
        float acc = 0.f;
        bool useW  = (mcase == 1);
        bool useZ  = (i > 0) && (mcase == 2 || mcase == 3);
        bool useUV = (mcase == 1) || ((i > 0) && (mcase == 3));
        bool useJ  = (i > 0) && (mcase == 2);
        if (useW && t > 0) acc += dot128<BF>(elem<BF>(Wk, r * HH), sh_hpk, c0);
        if (useZ && t > 0) acc += dot128<BF>(elem<BF>(Zk, r * HH), sh_hpkn, c0);
        if (useUV) {
            if (zb) {
                if (k > 0) acc += dot128<BF>(elem<BF>(Uk, r * (HH + GG)), sh_hlow, c0);
                acc += dot4<BF>(elem<BF>(Uk, r * (HH + GG) + HH), sh_x, g0);
            } else if (k > 0) {
                acc += dot128<BF>(elem<BF>(Vk, r * HH), sh_hlow, c0);
            }
        }
        if (useJ && zb) acc += dot4<BF>(elem<BF>(Jk, r * GG), sh_x, g0);
        sh_part[i * 256 + tid] = acc;
    }
    __syncthreads();

    if (tid < 64) {  // lane == tid here; j = jt*64 + tid
        float pre[5];
#pragma unroll
        for (int i = 0; i < 5; ++i)
            pre[i] = ldv<BF>(bbias, (size_t)k * FIVE_H + i * HH + j) +
                     sh_part[i * 256 + tid] + sh_part[i * 256 + 64 + tid] +
                     sh_part[i * 256 + 128 + tid] + sh_part[i * 256 + 192 + tid];
        float f  = 1.f / (1.f + expf(-pre[0]));   // forget gate: m1-only terms by construction
        float g  = tanhf(pre[1]);
        float ii = 1.f / (1.f + expf(-pre[2]));
        float o  = 1.f / (1.f + expf(-pre[3]));
        float sgv = fminf(fmaxf((pre[4] + 1.f) * 0.5f, 0.f), 1.f);

        size_t cidx = ((size_t)k * BB + b) * HH + j;
        float cp = c_buf[cidx];
        float cn = (mcase == 1) ? (f * cp + ii * g)
                 : (mcase == 4) ? cp
                                : (ii * g);
        float hpv = sh_hpk[j];
        float hn = (mcase == 4) ? (o * tanhf(cn)) : hpv;
        c_buf[cidx] = cn;
        hcur_sl[((size_t)k * BB + b) * HH + j] = hn;
        hhist[(((size_t)t * LL + k) * BB + b) * HH + j] = f2bf_rne(hn);

        float s = sgv;
#pragma unroll
        for (int off = 32; off > 0; off >>= 1) s += __shfl_down(s, off);
        if (tid == 0) atomicAdd(&sgsum[t * LL + k], s);
    }
}

__global__ __launch_bounds__(256) void step_kernel(
    const void* xin, const void* Wm, const void* Zm, const void* Um,
    const void* Vm, const void* Jm, const void* bbias, const void* bnd,
    float* ws, int t, int k) {
    extern __shared__ float smem[];
    int mode = ((const int*)ws)[0];
    if (mode) step_body<true>(xin, Wm, Zm, Um, Vm, Jm, bbias, bnd, ws, smem, t, k);
    else      step_body<false>(xin, Wm, Zm, Um, Vm, Jm, bbias, bnd, ws, smem, t, k);
}

template <bool BF>
__device__ void excite_body(const float* ws, float* smem, const void* Qm,
                            const void* Rm, const void* Wom, const void* bom,
                            void* out) {
    float (*sh_hcat)[LL * HH] = (float(*)[LL * HH])smem;          // TT x 2048
    float (*sh_r)[HH] = (float(*)[HH])(smem + TT * LL * HH);      // TT x 512
    const u16* hhist = (const u16*)(ws + HH_OFF);
    int tid = threadIdx.x;
    int b = blockIdx.x >> 5;
    int t0 = (blockIdx.x & 31) * TT;

    for (int idx = tid; idx < TT * LL * HH; idx += 256) {
        int tt = idx / (LL * HH);
        int f = idx % (LL * HH);
        int kk = f / HH, j = f % HH;
        sh_hcat[tt][f] = bf2f(hhist[(((size_t)(t0 + tt) * LL + kk) * BB + b) * HH + j]);
    }
    __syncthreads();

    int h0 = tid * 2;
    float acc0[TT] = {0, 0, 0, 0}, acc1[TT] = {0, 0, 0, 0};
    for (int kk = 0; kk < LL; ++kk) {
        float r0[TT] = {0, 0, 0, 0}, r1[TT] = {0, 0, 0, 0};
        if (BF) {
            const u32* qp = (const u32*)((const u16*)Qm + (size_t)kk * (LL * HH) * HH) + tid;
#pragma unroll 4
            for (int f = 0; f < LL * HH; ++f) {
                float2 qv = bf2x2(qp[(size_t)f * 256]);
#pragma unroll
                for (int tt = 0; tt < TT; ++tt) {
                    float hc = sh_hcat[tt][f];
                    r0[tt] += qv.x * hc;
                    r1[tt] += qv.y * hc;
                }
            }
        } else {
            const float2* qp = (const float2*)((const float*)Qm + (size_t)kk * (LL * HH) * HH) + tid;
#pragma unroll 4
            for (int f = 0; f < LL * HH; ++f) {
                float2 qv = qp[(size_t)f * 256];
#pragma unroll
                for (int tt = 0; tt < TT; ++tt) {
                    float hc = sh_hcat[tt][f];
                    r0[tt] += qv.x * hc;
                    r1[tt] += qv.y * hc;
                }
            }
        }
        __syncthreads();
#pragma unroll
        for (int tt = 0; tt < TT; ++tt) {
            sh_r[tt][h0]     = 1.f / (1.f + expf(-r0[tt]));
            sh_r[tt][h0 + 1] = 1.f / (1.f + expf(-r1[tt]));
        }
        __syncthreads();
        float m0[TT] = {0, 0, 0, 0}, m1v[TT] = {0, 0, 0, 0};
        if (BF) {
            const u32* rp = (const u32*)((const u16*)Rm + (size_t)kk * HH * HH) + tid;
#pragma unroll 4
            for (int hh2 = 0; hh2 < HH; ++hh2) {
                float2 rv = bf2x2(rp[(size_t)hh2 * 256]);
#pragma unroll
                for (int tt = 0; tt < TT; ++tt) {
                    float rr = sh_r[tt][hh2];
                    m0[tt] += rv.x * rr;
                    m1v[tt] += rv.y * rr;
                }
            }
        } else {
            const float2* rp = (const float2*)((const float*)Rm + (size_t)kk * HH * HH) + tid;
#pragma unroll 4
            for (int hh2 = 0; hh2 < HH; ++hh2) {
                float2 rv = rp[(size_t)hh2 * 256];
#pragma unroll
                for (int tt = 0; tt < TT; ++tt) {
                    float rr = sh_r[tt][hh2];
                    m0[tt] += rv.x * rr;
                    m1v[tt] += rv.y * rr;
                }
            }
        }
#pragma unroll
        for (int tt = 0; tt < TT; ++tt) {
            acc0[tt] += m0[tt] * sh_hcat[tt][kk * HH + h0];
            acc1[tt] += m1v[tt] * sh_hcat[tt][kk * HH + h0 + 1];
        }
    }
    __syncthreads();
#pragma unroll
    for (int tt = 0; tt < TT; ++tt) {
        sh_r[tt][h0]     = fmaxf(acc0[tt], 0.f);
        sh_r[tt][h0 + 1] = fmaxf(acc1[tt], 0.f);
    }
    __syncthreads();
    {
        int tt = tid >> 6, f = tid & 63;
        float acc = 0.f;
        if (BF) {
            const uint4* wp = (const uint4*)((const u16*)Wom + (size_t)f * HH);
            const float4* ev = (const float4*)sh_r[tt];
#pragma unroll 8
            for (int it = 0; it < HH / 8; ++it) {
                uint4 q = wp[it];
                float4 e0 = ev[2 * it], e1 = ev[2 * it + 1];
                float2 a0 = bf2x2(q.x), a1 = bf2x2(q.y), a2 = bf2x2(q.z), a3 = bf2x2(q.w);
                acc += a0.x * e0.x + a0.y * e0.y + a1.x * e0.z + a1.y * e0.w +
                       a2.x * e1.x + a2.y * e1.y + a3.x * e1.z + a3.y * e1.w;
            }
        } else {
            const float4* wp = (const float4*)((const float*)Wom + (size_t)f * HH);
            const float4* ev = (const float4*)sh_r[tt];
#pragma unroll 8
            for (int it = 0; it < HH / 4; ++it) {
                float4 q = wp[it], e = ev[it];
                acc += q.x * e.x + q.y * e.y + q.z * e.z + q.w * e.w;
            }
        }
        acc += ldv<BF>(bom, f);
        size_t oidx = ((size_t)b * TS + (t0 + tt)) * FF + f;
        if (BF) ((u16*)out)[oidx] = f2bf_rne(acc);
        else    ((float*)out)[oidx] = acc;
    }
}

__global__ __launch_bounds__(256) void excite_kernel(
    const float* ws, const void* Qm, const void* Rm, const void* Wom,
    const void* bom, void* out) {
    extern __shared__ float smem[];
    int mode = ((const int*)ws)[0];
    if (mode) excite_body<true>(ws, smem, Qm, Rm, Wom, bom, out);
    else      excite_body<false>(ws, smem, Qm, Rm, Wom, bom, out);
}

extern "C" void kernel_launch(void* const* d_in, const int* in_sizes, int n_in,
                              void* d_out, int out_size, void* d_ws, size_t ws_size,
                              hipStream_t stream) {
    const void* xin = d_in[0];
    const void* Wm  = d_in[1];
    const void* Zm  = d_in[2];
    const void* Um  = d_in[3];
    const void* Vm  = d_in[4];
    const void* Jm  = d_in[5];
    const void* bb  = d_in[6];
    const void* bnd = d_in[7];
    const void* Qm  = d_in[8];
    const void* Rm  = d_in[9];
    const void* Wo  = d_in[10];
    const void* bo  = d_in[11];
    float* ws = (float*)d_ws;

    init_kernel<<<dim3(512), dim3(256), 0, stream>>>((const u16*)bnd, ws);
    size_t step_smem = 2848 * sizeof(float);   // ~11.4 KB
    for (int t = 0; t < TS; ++t)
        for (int k = 0; k < LL; ++k)
            step_kernel<<<dim3(512), dim3(256), step_smem, stream>>>(
                xin, Wm, Zm, Um, Vm, Jm, bb, bnd, ws, t, k);
    size_t exc_smem = (TT * LL * HH + TT * HH) * sizeof(float);  // 40 KB
    excite_kernel<<<dim3(2048), dim3(256), exc_smem, stream>>>(
        ws, Qm, Rm, Wo, bo, d_out);
}

// Round 3
// 11607.462 us; speedup vs baseline: 1.5639x; 1.5639x over previous
//
#include <hip/hip_runtime.h>
#include <hip/hip_bf16.h>

// ---------------------------------------------------------------------------
// StandardMRALSTM — round 3: restructured scan (GEMM-tile + gates kernels).
//  * Dual-dtype (runtime-sniffed bf16/f32 inputs), all math fp32.
//  * Key insight: o-gate rows never need a matmul (h only updates in m4 where
//    pre=bias); f-gate only in m1; m4 steps skip GEMM entirely.
//  * Per step: gemm_kernel (grid 384; 64r x 64b x 128K tiles, LDS-staged,
//    coalesced) writes pre_part[12 slots][4 gates][64 b][512 j];
//    gates_kernel (grid 128) sums partials + bias + x-dots, updates c/h/s.
//  * ws (~39.5 MB): mode | sgsum[512] | zall[512] | zmask[512] u64 | c |
//    h-ping x2 | pre_part 6.3MB | h_hist bf16 32MB.
// ---------------------------------------------------------------------------

#define LL 4
#define HH 512
#define TS 128
#define GG 16
#define BB 64
#define FF 64
#define TT 4
#define FIVE_H 2560
#define LBH (LL * BB * HH)

typedef unsigned short u16;
typedef unsigned int u32;
typedef unsigned long long u64;

#define SG_OFF    64
#define ZALL_OFF  1024
#define ZMASK_OFF 2048
#define C_OFF     4096
#define PING_OFF  (C_OFF + LBH)              // 135168
#define PART_OFF  (PING_OFF + 2 * LBH)       // 397312
#define HIST_OFF  (PART_OFF + 12 * 4 * BB * HH)  // 1970176 (u16 region)

__device__ __forceinline__ float bf2f(u16 u) { return __uint_as_float(((u32)u) << 16); }
__device__ __forceinline__ float2 bf2x2(u32 u) {
    float2 r;
    r.x = __uint_as_float(u << 16);
    r.y = __uint_as_float(u & 0xFFFF0000u);
    return r;
}
__device__ __forceinline__ u16 f2bf_rne(float f) {
    u32 x = __float_as_uint(f);
    return (u16)((x + 0x7FFFu + ((x >> 16) & 1u)) >> 16);
}
__device__ __forceinline__ float sigm(float x) { return 1.f / (1.f + expf(-x)); }

template <bool BF>
__device__ __forceinline__ float ldv(const void* p, size_t i) {
    return BF ? bf2f(((const u16*)p)[i]) : ((const float*)p)[i];
}

template <bool BF>
__device__ __forceinline__ float dot16(const void* row, const float* xs) {
    float s = 0.f;
    if (BF) {
        const uint4* p = (const uint4*)row;
        uint4 a = p[0], b4 = p[1];
        float2 v;
        v = bf2x2(a.x);  s += v.x * xs[0]  + v.y * xs[1];
        v = bf2x2(a.y);  s += v.x * xs[2]  + v.y * xs[3];
        v = bf2x2(a.z);  s += v.x * xs[4]  + v.y * xs[5];
        v = bf2x2(a.w);  s += v.x * xs[6]  + v.y * xs[7];
        v = bf2x2(b4.x); s += v.x * xs[8]  + v.y * xs[9];
        v = bf2x2(b4.y); s += v.x * xs[10] + v.y * xs[11];
        v = bf2x2(b4.z); s += v.x * xs[12] + v.y * xs[13];
        v = bf2x2(b4.w); s += v.x * xs[14] + v.y * xs[15];
    } else {
        const float4* p = (const float4*)row;
#pragma unroll
        for (int i = 0; i < 4; ++i) {
            float4 v = p[i];
            s += v.x * xs[4 * i] + v.y * xs[4 * i + 1] + v.z * xs[4 * i + 2] + v.w * xs[4 * i + 3];
        }
    }
    return s;
}

// ---- init A: zero c + sgsum, sniff dtype from boundary raw bits ------------
__global__ void initA_kernel(const u16* __restrict__ bnd_raw, float* __restrict__ ws) {
    size_t i = (size_t)blockIdx.x * 256 + threadIdx.x;
    if (i < LBH) ws[C_OFF + i] = 0.f;
    if (i < 512) ws[SG_OFF + i] = 0.f;
    if (i == 0) {
        int bf = 1;
        for (int j = 0; j < 32; ++j) {
            float v = bf2f(bnd_raw[2 * j]);
            if (!(v >= 0.f && v <= 1.f)) bf = 0;
        }
        ((int*)ws)[0] = bf;
    }
}

// ---- init B: per-(t,k) z bitmask over batches ------------------------------
template <bool BF>
__device__ void initB_body(const void* xin, float* ws) {
    int tk = blockIdx.x;
    int t = tk >> 2, k = tk & 3;
    int b = threadIdx.x;
    bool z = false;
    size_t base = (size_t)b * TS * FF + (size_t)t * FF + k * GG;
#pragma unroll
    for (int g = 0; g < GG; ++g) {
        float v = ldv<BF>(xin, base + g);
        z |= !(v != v);
    }
    u64 m = __ballot(z);
    if (b == 0) {
        ((u64*)(ws + ZMASK_OFF))[tk] = m;
        ((int*)(ws + ZALL_OFF))[tk] = (m == ~0ull) ? 1 : 0;
    }
}
__global__ __launch_bounds__(64) void initB_kernel(const void* xin, float* ws) {
    int mode = ((const int*)ws)[0];
    if (mode) initB_body<true>(xin, ws);
    else      initB_body<false>(xin, ws);
}

// ---- per-step GEMM ---------------------------------------------------------
template <bool BF>
__device__ void gemm_body(const void* Wm, const void* Zm, const void* Um, const void* Vm,
                          const void* bnd, float* ws, float* wt, float* ht, int t, int k) {
    int tid = threadIdx.x;
    int q = blockIdx.x & 3, sub = (blockIdx.x >> 2) & 7, unit = blockIdx.x >> 5;
    const float* sgsum = ws + SG_OFF;

    bool p_hi = (t == 0) ? (ldv<BF>(bnd, (size_t)k * TS) > 0.5f) : (sgsum[(t - 1) * 4 + k] > 16384.f);
    bool l_hi = (k == 0) ? (ldv<BF>(bnd, (size_t)t) > 0.5f) : (sgsum[t * 4 + (k - 1)] > 16384.f);
    int mcase = p_hi ? (l_hi ? 3 : 2) : (l_hi ? 1 : 4);
    if (mcase == 4) return;
    int azf = ((int*)(ws + ZALL_OFF))[t * 4 + k] ? 0 : 1;

    int gs = (mcase == 1) ? 0 : 1, ng = 4 - gs;
    int nW = (t > 0) ? ng : 0;
    int nU = ((mcase == 1 || mcase == 3) && k > 0) ? ng : 0;
    int nV = azf ? nU : 0;
    if (unit >= nW + nU + nV) return;

    int mat, g;
    if (unit < nW)            { mat = (mcase == 1) ? 0 : 1; g = gs + unit; }
    else if (unit < nW + nU)  { mat = 2; g = gs + unit - nW; }
    else                      { mat = 3; g = gs + unit - nW - nU; }

    const void* M = (mat == 0) ? Wm : (mat == 1) ? Zm : (mat == 2) ? Um : Vm;
    int RS = (mat == 2) ? (HH + GG) : HH;
    int gbase = (g < 3) ? g * 512 : 2048;
    size_t mbase = (size_t)k * FIVE_H * RS + (size_t)(gbase + sub * 64) * RS + q * 128;
    int kn = (k + 1 < LL) ? k + 1 : LL - 1;
    const float* ping = ws + PING_OFF;
    const float* prev = ping + (size_t)((t + 1) & 1) * LBH;
    const float* cur  = ping + (size_t)(t & 1) * LBH;
    const float* hv = (mat == 0) ? prev + (size_t)k * BB * HH
                    : (mat == 1) ? prev + (size_t)kn * BB * HH
                                 : cur + (size_t)(k - 1) * BB * HH;
    int path = (mat <= 1) ? 0 : (mat == 2 ? 1 : 2);

    int rg = tid >> 4, bg = tid & 15;        // thread tile: rows rg*4.., batches bg*4..
    float acc[4][4] = {{0.f}};

    for (int half = 0; half < 2; ++half) {
        // stage weights [r][k] fp32 and h [k][b] fp32
        int sr = tid >> 2, scg = (tid & 3) * 16;
        size_t rowoff = mbase + (size_t)sr * RS + half * 64 + scg;
#pragma unroll
        for (int i = 0; i < 4; ++i) {
            float4 v;
            if (BF) {
                uint2 u2 = *(const uint2*)((const u16*)M + rowoff + 4 * i);
                float2 a = bf2x2(u2.x), c2 = bf2x2(u2.y);
                v = make_float4(a.x, a.y, c2.x, c2.y);
            } else {
                v = *(const float4*)((const float*)M + rowoff + 4 * i);
            }
            *(float4*)&wt[sr * 68 + scg + 4 * i] = v;
        }
        const float* hr = hv + (size_t)sr * HH + q * 128 + half * 64 + scg;
#pragma unroll
        for (int i = 0; i < 4; ++i) {
            float4 v = *(const float4*)(hr + 4 * i);
            int kk = scg + 4 * i;
            ht[(kk + 0) * 68 + sr] = v.x;
            ht[(kk + 1) * 68 + sr] = v.y;
            ht[(kk + 2) * 68 + sr] = v.z;
            ht[(kk + 3) * 68 + sr] = v.w;
        }
        __syncthreads();
#pragma unroll 4
        for (int kk4 = 0; kk4 < 64; kk4 += 4) {
            float w[4][4], h[4][4];
#pragma unroll
            for (int j = 0; j < 4; ++j)
                *(float4*)w[j] = *(const float4*)&wt[(rg * 4 + j) * 68 + kk4];
#pragma unroll
            for (int j = 0; j < 4; ++j)
                *(float4*)h[j] = *(const float4*)&ht[(kk4 + j) * 68 + bg * 4];
#pragma unroll
            for (int rj = 0; rj < 4; ++rj)
#pragma unroll
                for (int bj = 0; bj < 4; ++bj)
#pragma unroll
                    for (int j = 0; j < 4; ++j)
                        acc[rj][bj] += w[rj][j] * h[j][bj];
        }
        __syncthreads();
    }

    float* pout = ws + PART_OFF + ((size_t)(path * 4 + q) * 4 + g) * (size_t)BB * HH;
#pragma unroll
    for (int bj = 0; bj < 4; ++bj) {
        float4 vv = make_float4(acc[0][bj], acc[1][bj], acc[2][bj], acc[3][bj]);
        *(float4*)&pout[(size_t)(bg * 4 + bj) * HH + sub * 64 + rg * 4] = vv;
    }
}

__global__ __launch_bounds__(256) void gemm_kernel(
    const void* Wm, const void* Zm, const void* Um, const void* Vm,
    const void* bnd, float* ws, int t, int k) {
    __shared__ float wt[64 * 68];
    __shared__ float ht[64 * 68];
    int mode = ((const int*)ws)[0];
    if (mode) gemm_body<true>(Wm, Zm, Um, Vm, bnd, ws, wt, ht, t, k);
    else      gemm_body<false>(Wm, Zm, Um, Vm, bnd, ws, wt, ht, t, k);
}

// ---- per-step gates --------------------------------------------------------
template <bool BF>
__device__ void gates_body(const void* xin, const void* Um, const void* Jm,
                           const void* bbias, const void* bnd,
                           float* ws, float xs[4][17], int t, int k) {
    int tid = threadIdx.x;
    int j = ((blockIdx.x & 7) << 6) + (tid & 63);
    int bl = tid >> 6;
    int bbase = (blockIdx.x >> 3) << 2;
    int b = bbase + bl;

    float* sgsum = ws + SG_OFF;
    bool p_hi = (t == 0) ? (ldv<BF>(bnd, (size_t)k * TS) > 0.5f) : (sgsum[(t - 1) * 4 + k] > 16384.f);
    bool l_hi = (k == 0) ? (ldv<BF>(bnd, (size_t)t) > 0.5f) : (sgsum[t * 4 + (k - 1)] > 16384.f);
    int mcase = p_hi ? (l_hi ? 3 : 2) : (l_hi ? 1 : 4);
    int azf = ((int*)(ws + ZALL_OFF))[t * 4 + k] ? 0 : 1;

    if (tid < 64) {
        int sbl = tid >> 4, i = tid & 15;
        float v = ldv<BF>(xin, (size_t)(bbase + sbl) * TS * FF + (size_t)t * FF + k * GG + i);
        xs[sbl][i] = (v != v) ? 0.f : v;
    }
    __syncthreads();
    u64 zm = ((const u64*)(ws + ZMASK_OFF))[t * 4 + k];
    bool zb = (zm >> b) & 1ull;

    float* cbuf = ws + C_OFF;
    const float* part = ws + PART_OFF;
    float* cur = ws + PING_OFF + (size_t)(t & 1) * LBH;
    const float* prev = ws + PING_OFF + (size_t)((t + 1) & 1) * LBH;
    u16* hist = (u16*)(ws + HIST_OFF);
    size_t sidx = ((size_t)k * BB + b) * HH + j;

    float hn, sgv;
    if (mcase == 4) {
        float c = cbuf[sidx];
        float o = sigm(ldv<BF>(bbias, (size_t)k * FIVE_H + 1536 + j));
        hn = o * tanhf(c);
        float bsg = ldv<BF>(bbias, (size_t)k * FIVE_H + 2048 + j);
        sgv = fminf(fmaxf((bsg + 1.f) * 0.5f, 0.f), 1.f);
    } else {
        bool hasWZ = (t > 0);
        bool hasU = (k > 0) && (mcase != 2);
        const float* xv = &xs[bl][0];

        auto psum = [&](int path, int g) -> float {
            float s = 0.f;
#pragma unroll
            for (int qq = 0; qq < 4; ++qq)
                s += part[(((size_t)(path * 4 + qq) * 4 + g) * BB + b) * HH + j];
            return s;
        };
        auto pre = [&](int g) -> float {
            int gb = (g < 3) ? g * 512 : 2048;
            float s = ldv<BF>(bbias, (size_t)k * FIVE_H + gb + j);
            if (hasWZ) s += psum(0, g);
            if (mcase == 2) {
                if (zb) {
                    const void* row = BF ? (const void*)((const u16*)Jm + (size_t)k * FIVE_H * GG + (size_t)(gb + j) * GG)
                                         : (const void*)((const float*)Jm + (size_t)k * FIVE_H * GG + (size_t)(gb + j) * GG);
                    s += dot16<BF>(row, xv);
                }
            } else {
                if (zb) {
                    if (hasU) s += psum(1, g);
                    const void* row = BF ? (const void*)((const u16*)Um + (size_t)k * FIVE_H * (HH + GG) + (size_t)(gb + j) * (HH + GG) + HH)
                                         : (const void*)((const float*)Um + (size_t)k * FIVE_H * (HH + GG) + (size_t)(gb + j) * (HH + GG) + HH);
                    s += dot16<BF>(row, xv);
                } else {
                    if (hasU && azf) s += psum(2, g);
                }
            }
            return s;
        };
        float preg = pre(1), prei = pre(2), presg = pre(3);
        float gg = tanhf(preg), ii = sigm(prei);
        float cnew;
        if (mcase == 1) {
            float f = sigm(pre(0));
            cnew = f * cbuf[sidx] + ii * gg;
        } else {
            cnew = ii * gg;
        }
        cbuf[sidx] = cnew;
        hn = (t > 0) ? prev[sidx] : 0.f;
        sgv = fminf(fmaxf((presg + 1.f) * 0.5f, 0.f), 1.f);
    }
    cur[sidx] = hn;
    hist[((size_t)(t * 4 + k) * BB + b) * HH + j] = f2bf_rne(hn);

    float s = sgv;
#pragma unroll
    for (int off = 32; off > 0; off >>= 1) s += __shfl_down(s, off);
    if ((tid & 63) == 0) atomicAdd(&sgsum[t * 4 + k], s);
}

__global__ __launch_bounds__(256) void gates_kernel(
    const void* xin, const void* Um, const void* Jm, const void* bbias,
    const void* bnd, float* ws, int t, int k) {
    __shared__ float xs[4][17];
    int mode = ((const int*)ws)[0];
    if (mode) gates_body<true>(xin, Um, Jm, bbias, bnd, ws, xs, t, k);
    else      gates_body<false>(xin, Um, Jm, bbias, bnd, ws, xs, t, k);
}

// ---- excitation epilogue (round-2, hist offset updated) --------------------
template <bool BF>
__device__ void excite_body(const float* ws, float* smem, const void* Qm,
                            const void* Rm, const void* Wom, const void* bom,
                            void* out) {
    float (*sh_hcat)[LL * HH] = (float(*)[LL * HH])smem;
    float (*sh_r)[HH] = (float(*)[HH])(smem + TT * LL * HH);
    const u16* hhist = (const u16*)(ws + HIST_OFF);
    int tid = threadIdx.x;
    int b = blockIdx.x >> 5;
    int t0 = (blockIdx.x & 31) * TT;

    for (int idx = tid; idx < TT * LL * HH; idx += 256) {
        int tt = idx / (LL * HH);
        int f = idx % (LL * HH);
        int kk = f / HH, j = f % HH;
        sh_hcat[tt][f] = bf2f(hhist[(((size_t)(t0 + tt) * LL + kk) * BB + b) * HH + j]);
    }
    __syncthreads();

    int h0 = tid * 2;
    float acc0[TT] = {0, 0, 0, 0}, acc1[TT] = {0, 0, 0, 0};
    for (int kk = 0; kk < LL; ++kk) {
        float r0[TT] = {0, 0, 0, 0}, r1[TT] = {0, 0, 0, 0};
        if (BF) {
            const u32* qp = (const u32*)((const u16*)Qm + (size_t)kk * (LL * HH) * HH) + tid;
#pragma unroll 4
            for (int f = 0; f < LL * HH; ++f) {
                float2 qv = bf2x2(qp[(size_t)f * 256]);
#pragma unroll
                for (int tt = 0; tt < TT; ++tt) {
                    float hc = sh_hcat[tt][f];
                    r0[tt] += qv.x * hc;
                    r1[tt] += qv.y * hc;
                }
            }
        } else {
            const float2* qp = (const float2*)((const float*)Qm + (size_t)kk * (LL * HH) * HH) + tid;
#pragma unroll 4
            for (int f = 0; f < LL * HH; ++f) {
                float2 qv = qp[(size_t)f * 256];
#pragma unroll
                for (int tt = 0; tt < TT; ++tt) {
                    float hc = sh_hcat[tt][f];
                    r0[tt] += qv.x * hc;
                    r1[tt] += qv.y * hc;
                }
            }
        }
        __syncthreads();
#pragma unroll
        for (int tt = 0; tt < TT; ++tt) {
            sh_r[tt][h0]     = 1.f / (1.f + expf(-r0[tt]));
            sh_r[tt][h0 + 1] = 1.f / (1.f + expf(-r1[tt]));
        }
        __syncthreads();
        float m0[TT] = {0, 0, 0, 0}, m1v[TT] = {0, 0, 0, 0};
        if (BF) {
            const u32* rp = (const u32*)((const u16*)Rm + (size_t)kk * HH * HH) + tid;
#pragma unroll 4
            for (int hh2 = 0; hh2 < HH; ++hh2) {
                float2 rv = bf2x2(rp[(size_t)hh2 * 256]);
#pragma unroll
                for (int tt = 0; tt < TT; ++tt) {
                    float rr = sh_r[tt][hh2];
                    m0[tt] += rv.x * rr;
                    m1v[tt] += rv.y * rr;
                }
            }
        } else {
            const float2* rp = (const float2*)((const float*)Rm + (size_t)kk * HH * HH) + tid;
#pragma unroll 4
            for (int hh2 = 0; hh2 < HH; ++hh2) {
                float2 rv = rp[(size_t)hh2 * 256];
#pragma unroll
                for (int tt = 0; tt < TT; ++tt) {
                    float rr = sh_r[tt][hh2];
                    m0[tt] += rv.x * rr;
                    m1v[tt] += rv.y * rr;
                }
            }
        }
#pragma unroll
        for (int tt = 0; tt < TT; ++tt) {
            acc0[tt] += m0[tt] * sh_hcat[tt][kk * HH + h0];
            acc1[tt] += m1v[tt] * sh_hcat[tt][kk * HH + h0 + 1];
        }
    }
    __syncthreads();
#pragma unroll
    for (int tt = 0; tt < TT; ++tt) {
        sh_r[tt][h0]     = fmaxf(acc0[tt], 0.f);
        sh_r[tt][h0 + 1] = fmaxf(acc1[tt], 0.f);
    }
    __syncthreads();
    {
        int tt = tid >> 6, f = tid & 63;
        float acc = 0.f;
        if (BF) {
            const uint4* wp = (const uint4*)((const u16*)Wom + (size_t)f * HH);
            const float4* ev = (const float4*)sh_r[tt];
#pragma unroll 8
            for (int it = 0; it < HH / 8; ++it) {
                uint4 qv = wp[it];
                float4 e0 = ev[2 * it], e1 = ev[2 * it + 1];
                float2 a0 = bf2x2(qv.x), a1 = bf2x2(qv.y), a2 = bf2x2(qv.z), a3 = bf2x2(qv.w);
                acc += a0.x * e0.x + a0.y * e0.y + a1.x * e0.z + a1.y * e0.w +
                       a2.x * e1.x + a2.y * e1.y + a3.x * e1.z + a3.y * e1.w;
            }
        } else {
            const float4* wp = (const float4*)((const float*)Wom + (size_t)f * HH);
            const float4* ev = (const float4*)sh_r[tt];
#pragma unroll 8
            for (int it = 0; it < HH / 4; ++it) {
                float4 qv = wp[it], e = ev[it];
                acc += qv.x * e.x + qv.y * e.y + qv.z * e.z + qv.w * e.w;
            }
        }
        acc += ldv<BF>(bom, f);
        size_t oidx = ((size_t)b * TS + (t0 + tt)) * FF + f;
        if (BF) ((u16*)out)[oidx] = f2bf_rne(acc);
        else    ((float*)out)[oidx] = acc;
    }
}

__global__ __launch_bounds__(256) void excite_kernel(
    const float* ws, const void* Qm, const void* Rm, const void* Wom,
    const void* bom, void* out) {
    extern __shared__ float smem[];
    int mode = ((const int*)ws)[0];
    if (mode) excite_body<true>(ws, smem, Qm, Rm, Wom, bom, out);
    else      excite_body<false>(ws, smem, Qm, Rm, Wom, bom, out);
}

extern "C" void kernel_launch(void* const* d_in, const int* in_sizes, int n_in,
                              void* d_out, int out_size, void* d_ws, size_t ws_size,
                              hipStream_t stream) {
    const void* xin = d_in[0];
    const void* Wm  = d_in[1];
    const void* Zm  = d_in[2];
    const void* Um  = d_in[3];
    const void* Vm  = d_in[4];
    const void* Jm  = d_in[5];
    const void* bb  = d_in[6];
    const void* bnd = d_in[7];
    const void* Qm  = d_in[8];
    const void* Rm  = d_in[9];
    const void* Wo  = d_in[10];
    const void* bo  = d_in[11];
    float* ws = (float*)d_ws;

    initA_kernel<<<dim3(512), dim3(256), 0, stream>>>((const u16*)bnd, ws);
    initB_kernel<<<dim3(512), dim3(64), 0, stream>>>(xin, ws);
    for (int t = 0; t < TS; ++t)
        for (int k = 0; k < LL; ++k) {
            gemm_kernel<<<dim3(384), dim3(256), 0, stream>>>(Wm, Zm, Um, Vm, bnd, ws, t, k);
            gates_kernel<<<dim3(128), dim3(256), 0, stream>>>(xin, Um, Jm, bb, bnd, ws, t, k);
        }
    size_t exc_smem = (TT * LL * HH + TT * HH) * sizeof(float);  // 40 KB
    excite_kernel<<<dim3(2048), dim3(256), exc_smem, stream>>>(
        ws, Qm, Rm, Wo, bo, d_out);
}

// Round 4
// 8863.255 us; speedup vs baseline: 2.0481x; 1.3096x over previous
//
#include <hip/hip_runtime.h>
#include <hip/hip_bf16.h>

// ---------------------------------------------------------------------------
// StandardMRALSTM — round 4: wavefront scan (tau = 2t+k, 258 phases) +
// b-minor layouts for coalescing.
//  * Dual-dtype (runtime-sniffed bf16/f32 inputs), all math fp32.
//  * Phase tau: cells (t,k) with k=(tau&1)+2*seg, t=(tau-k)/2, seg in {0,1}.
//    Deps: (t,k-1)->tau-1, (t-1,k)->tau-2, (t-1,k+1)->tau-1  => all earlier.
//  * gemm_kernel grid 768 (2 segs x 12 units x 8 sub x 4 q): 64r x 64b x 128K
//    tiles; h ping stored [k][c][b] so h-staging is direct b128 (no transpose).
//  * gates_kernel grid 256 (2 segs x 128): lane=b mapping, coalesced.
//  * ws (~48 MB): mode | sgsum | zall | zmask | c[k][j][b] | ping[2][k][c][b]
//    | part[2 seg][12 slot][4 gate][512 j][64 b] | hist bf16 [t][k][b][j].
// ---------------------------------------------------------------------------

#define LL 4
#define HH 512
#define TS 128
#define GG 16
#define BB 64
#define FF 64
#define TT 4
#define FIVE_H 2560
#define LBH (LL * BB * HH)

typedef unsigned short u16;
typedef unsigned int u32;
typedef unsigned long long u64;

#define SG_OFF    64
#define ZALL_OFF  1024
#define ZMASK_OFF 2048
#define C_OFF     4096
#define PING_OFF  (C_OFF + LBH)                       // 135168
#define PART_OFF  (PING_OFF + 2 * LBH)                // 397312
#define PART_SEG  (12 * 4 * HH * BB)                  // 1572864 floats per seg
#define HIST_OFF  (PART_OFF + 2 * PART_SEG)           // 3543040 (u16 region)

__device__ __forceinline__ float bf2f(u16 u) { return __uint_as_float(((u32)u) << 16); }
__device__ __forceinline__ float2 bf2x2(u32 u) {
    float2 r;
    r.x = __uint_as_float(u << 16);
    r.y = __uint_as_float(u & 0xFFFF0000u);
    return r;
}
__device__ __forceinline__ u16 f2bf_rne(float f) {
    u32 x = __float_as_uint(f);
    return (u16)((x + 0x7FFFu + ((x >> 16) & 1u)) >> 16);
}
__device__ __forceinline__ float sigm(float x) { return 1.f / (1.f + expf(-x)); }

template <bool BF>
__device__ __forceinline__ float ldv(const void* p, size_t i) {
    return BF ? bf2f(((const u16*)p)[i]) : ((const float*)p)[i];
}

template <bool BF>
__device__ __forceinline__ float dot16(const void* row, const float* xs) {
    float s = 0.f;
    if (BF) {
        const uint4* p = (const uint4*)row;
        uint4 a = p[0], b4 = p[1];
        float2 v;
        v = bf2x2(a.x);  s += v.x * xs[0]  + v.y * xs[1];
        v = bf2x2(a.y);  s += v.x * xs[2]  + v.y * xs[3];
        v = bf2x2(a.z);  s += v.x * xs[4]  + v.y * xs[5];
        v = bf2x2(a.w);  s += v.x * xs[6]  + v.y * xs[7];
        v = bf2x2(b4.x); s += v.x * xs[8]  + v.y * xs[9];
        v = bf2x2(b4.y); s += v.x * xs[10] + v.y * xs[11];
        v = bf2x2(b4.z); s += v.x * xs[12] + v.y * xs[13];
        v = bf2x2(b4.w); s += v.x * xs[14] + v.y * xs[15];
    } else {
        const float4* p = (const float4*)row;
#pragma unroll
        for (int i = 0; i < 4; ++i) {
            float4 v = p[i];
            s += v.x * xs[4 * i] + v.y * xs[4 * i + 1] + v.z * xs[4 * i + 2] + v.w * xs[4 * i + 3];
        }
    }
    return s;
}

// ---- init A: zero c + sgsum, sniff dtype ----------------------------------
__global__ void initA_kernel(const u16* __restrict__ bnd_raw, float* __restrict__ ws) {
    size_t i = (size_t)blockIdx.x * 256 + threadIdx.x;
    if (i < LBH) ws[C_OFF + i] = 0.f;
    if (i < 512) ws[SG_OFF + i] = 0.f;
    if (i == 0) {
        int bf = 1;
        for (int j = 0; j < 32; ++j) {
            float v = bf2f(bnd_raw[2 * j]);
            if (!(v >= 0.f && v <= 1.f)) bf = 0;
        }
        ((int*)ws)[0] = bf;
    }
}

// ---- init B: per-(t,k) z bitmask over batches ------------------------------
template <bool BF>
__device__ void initB_body(const void* xin, float* ws) {
    int tk = blockIdx.x;
    int t = tk >> 2, k = tk & 3;
    int b = threadIdx.x;
    bool z = false;
    size_t base = (size_t)b * TS * FF + (size_t)t * FF + k * GG;
#pragma unroll
    for (int g = 0; g < GG; ++g) {
        float v = ldv<BF>(xin, base + g);
        z |= !(v != v);
    }
    u64 m = __ballot(z);
    if (b == 0) {
        ((u64*)(ws + ZMASK_OFF))[tk] = m;
        ((int*)(ws + ZALL_OFF))[tk] = (m == ~0ull) ? 1 : 0;
    }
}
__global__ __launch_bounds__(64) void initB_kernel(const void* xin, float* ws) {
    int mode = ((const int*)ws)[0];
    if (mode) initB_body<true>(xin, ws);
    else      initB_body<false>(xin, ws);
}

// ---- per-phase GEMM --------------------------------------------------------
template <bool BF>
__device__ void gemm_body(const void* Wm, const void* Zm, const void* Um, const void* Vm,
                          const void* bnd, float* ws, float* wt, float* ht, int tau) {
    int tid = threadIdx.x;
    int seg = blockIdx.x / 384;
    int idx = blockIdx.x - seg * 384;
    int q = idx & 3, sub = (idx >> 2) & 7, unit = idx >> 5;
    int k = (tau & 1) + 2 * seg;
    int t = (tau - k) >> 1;
    if (t < 0 || t >= TS) return;

    const float* sgsum = ws + SG_OFF;
    bool p_hi = (t == 0) ? (ldv<BF>(bnd, (size_t)k * TS) > 0.5f) : (sgsum[(t - 1) * 4 + k] > 16384.f);
    bool l_hi = (k == 0) ? (ldv<BF>(bnd, (size_t)t) > 0.5f) : (sgsum[t * 4 + (k - 1)] > 16384.f);
    int mcase = p_hi ? (l_hi ? 3 : 2) : (l_hi ? 1 : 4);
    if (mcase == 4) return;
    int azf = ((int*)(ws + ZALL_OFF))[t * 4 + k] ? 0 : 1;

    int gs = (mcase == 1) ? 0 : 1, ng = 4 - gs;
    int nW = (t > 0) ? ng : 0;
    int nU = ((mcase == 1 || mcase == 3) && k > 0) ? ng : 0;
    int nV = azf ? nU : 0;
    if (unit >= nW + nU + nV) return;

    int mat, g;
    if (unit < nW)            { mat = (mcase == 1) ? 0 : 1; g = gs + unit; }
    else if (unit < nW + nU)  { mat = 2; g = gs + unit - nW; }
    else                      { mat = 3; g = gs + unit - nW - nU; }

    const void* M = (mat == 0) ? Wm : (mat == 1) ? Zm : (mat == 2) ? Um : Vm;
    int RS = (mat == 2) ? (HH + GG) : HH;
    int gbase = (g < 3) ? g * 512 : 2048;
    size_t mbase = (size_t)k * FIVE_H * RS + (size_t)(gbase + sub * 64) * RS + q * 128;
    int kn = (k + 1 < LL) ? k + 1 : LL - 1;
    const float* ping = ws + PING_OFF;
    const float* prev = ping + (size_t)((t + 1) & 1) * LBH;   // [k][c][b]
    const float* cur  = ping + (size_t)(t & 1) * LBH;
    const float* hv = (mat == 0) ? prev + (size_t)k * HH * BB
                    : (mat == 1) ? prev + (size_t)kn * HH * BB
                                 : cur + (size_t)(k - 1) * HH * BB;
    int path = (mat <= 1) ? 0 : (mat == 2 ? 1 : 2);

    int rg = tid >> 4, bg = tid & 15;   // thread tile: rows rg*4.., batches bg*4..
    float acc[4][4] = {{0.f}};

    for (int half = 0; half < 2; ++half) {
        // weights [r][c] (row-major, coalesced)
        int sr = tid >> 2, scg = (tid & 3) * 16;
        size_t rowoff = mbase + (size_t)sr * RS + half * 64 + scg;
#pragma unroll
        for (int i = 0; i < 4; ++i) {
            float4 v;
            if (BF) {
                uint2 u2 = *(const uint2*)((const u16*)M + rowoff + 4 * i);
                float2 a = bf2x2(u2.x), c2 = bf2x2(u2.y);
                v = make_float4(a.x, a.y, c2.x, c2.y);
            } else {
                v = *(const float4*)((const float*)M + rowoff + 4 * i);
            }
            *(float4*)&wt[sr * 68 + scg + 4 * i] = v;
        }
        // h tile [c][b]: ping already transposed -> direct vector staging
        int hc = tid >> 2, hb = (tid & 3) * 16;
        const float* hrow = hv + (size_t)(q * 128 + half * 64 + hc) * BB + hb;
#pragma unroll
        for (int i = 0; i < 4; ++i)
            *(float4*)&ht[hc * 68 + hb + 4 * i] = *(const float4*)(hrow + 4 * i);
        __syncthreads();
#pragma unroll 4
        for (int kk4 = 0; kk4 < 64; kk4 += 4) {
            float w[4][4], h[4][4];
#pragma unroll
            for (int j = 0; j < 4; ++j)
                *(float4*)w[j] = *(const float4*)&wt[(rg * 4 + j) * 68 + kk4];
#pragma unroll
            for (int j = 0; j < 4; ++j)
                *(float4*)h[j] = *(const float4*)&ht[(kk4 + j) * 68 + bg * 4];
#pragma unroll
            for (int rj = 0; rj < 4; ++rj)
#pragma unroll
                for (int bj = 0; bj < 4; ++bj)
#pragma unroll
                    for (int j = 0; j < 4; ++j)
                        acc[rj][bj] += w[rj][j] * h[j][bj];
        }
        __syncthreads();
    }

    // partials [seg][slot][g][j][b]
    float* pout = ws + PART_OFF + (size_t)seg * PART_SEG +
                  ((size_t)(path * 4 + q) * 4 + g) * (size_t)HH * BB;
#pragma unroll
    for (int rj = 0; rj < 4; ++rj) {
        float4 vv = make_float4(acc[rj][0], acc[rj][1], acc[rj][2], acc[rj][3]);
        *(float4*)&pout[(size_t)(sub * 64 + rg * 4 + rj) * BB + bg * 4] = vv;
    }
}

__global__ __launch_bounds__(256) void gemm_kernel(
    const void* Wm, const void* Zm, const void* Um, const void* Vm,
    const void* bnd, float* ws, int tau) {
    __shared__ float wt[64 * 68];
    __shared__ float ht[64 * 68];
    int mode = ((const int*)ws)[0];
    if (mode) gemm_body<true>(Wm, Zm, Um, Vm, bnd, ws, wt, ht, tau);
    else      gemm_body<false>(Wm, Zm, Um, Vm, bnd, ws, wt, ht, tau);
}

// ---- per-phase gates (lane = b) -------------------------------------------
template <bool BF>
__device__ void gates_body(const void* xin, const void* Um, const void* Jm,
                           const void* bbias, const void* bnd,
                           float* ws, float xs[BB][GG + 1], int tau) {
    int tid = threadIdx.x;
    int seg = blockIdx.x >> 7;
    int jblk = blockIdx.x & 127;
    int k = (tau & 1) + 2 * seg;
    int t = (tau - k) >> 1;
    if (t < 0 || t >= TS) return;

    int j = jblk * 4 + (tid >> 6);
    int b = tid & 63;

    float* sgsum = ws + SG_OFF;
    bool p_hi = (t == 0) ? (ldv<BF>(bnd, (size_t)k * TS) > 0.5f) : (sgsum[(t - 1) * 4 + k] > 16384.f);
    bool l_hi = (k == 0) ? (ldv<BF>(bnd, (size_t)t) > 0.5f) : (sgsum[t * 4 + (k - 1)] > 16384.f);
    int mcase = p_hi ? (l_hi ? 3 : 2) : (l_hi ? 1 : 4);
    int azf = ((int*)(ws + ZALL_OFF))[t * 4 + k] ? 0 : 1;

    {   // stage x[b][0..15]
        int b2 = tid >> 2, i0 = (tid & 3) * 4;
#pragma unroll
        for (int i = 0; i < 4; ++i) {
            float v = ldv<BF>(xin, (size_t)b2 * TS * FF + (size_t)t * FF + k * GG + i0 + i);
            xs[b2][i0 + i] = (v != v) ? 0.f : v;
        }
    }
    __syncthreads();
    u64 zm = ((const u64*)(ws + ZMASK_OFF))[t * 4 + k];
    bool zb = (zm >> b) & 1ull;

    float* cbuf = ws + C_OFF;                      // [k][j][b]
    const float* part = ws + PART_OFF + (size_t)seg * PART_SEG;
    float* cur = ws + PING_OFF + (size_t)(t & 1) * LBH;
    const float* prev = ws + PING_OFF + (size_t)((t + 1) & 1) * LBH;
    u16* hist = (u16*)(ws + HIST_OFF);
    size_t sidx = ((size_t)k * HH + j) * BB + b;

    float hn, sgv;
    if (mcase == 4) {
        float c = cbuf[sidx];
        float o = sigm(ldv<BF>(bbias, (size_t)k * FIVE_H + 1536 + j));
        hn = o * tanhf(c);
        float bsg = ldv<BF>(bbias, (size_t)k * FIVE_H + 2048 + j);
        sgv = fminf(fmaxf((bsg + 1.f) * 0.5f, 0.f), 1.f);
    } else {
        bool hasWZ = (t > 0);
        bool hasU = (k > 0) && (mcase != 2);
        const float* xv = &xs[b][0];

        auto psum = [&](int path, int g) -> float {
            float s = 0.f;
#pragma unroll
            for (int qq = 0; qq < 4; ++qq)
                s += part[(((size_t)(path * 4 + qq) * 4 + g) * HH + j) * BB + b];
            return s;
        };
        auto pre = [&](int g) -> float {
            int gb = (g < 3) ? g * 512 : 2048;
            float s = ldv<BF>(bbias, (size_t)k * FIVE_H + gb + j);
            if (hasWZ) s += psum(0, g);
            if (mcase == 2) {
                if (zb) {
                    const void* row = BF ? (const void*)((const u16*)Jm + (size_t)k * FIVE_H * GG + (size_t)(gb + j) * GG)
                                         : (const void*)((const float*)Jm + (size_t)k * FIVE_H * GG + (size_t)(gb + j) * GG);
                    s += dot16<BF>(row, xv);
                }
            } else {
                if (zb) {
                    if (hasU) s += psum(1, g);
                    const void* row = BF ? (const void*)((const u16*)Um + (size_t)k * FIVE_H * (HH + GG) + (size_t)(gb + j) * (HH + GG) + HH)
                                         : (const void*)((const float*)Um + (size_t)k * FIVE_H * (HH + GG) + (size_t)(gb + j) * (HH + GG) + HH);
                    s += dot16<BF>(row, xv);
                } else {
                    if (hasU && azf) s += psum(2, g);
                }
            }
            return s;
        };
        float preg = pre(1), prei = pre(2), presg = pre(3);
        float gg = tanhf(preg), ii = sigm(prei);
        float cnew;
        if (mcase == 1) {
            float f = sigm(pre(0));
            cnew = f * cbuf[sidx] + ii * gg;
        } else {
            cnew = ii * gg;
        }
        cbuf[sidx] = cnew;
        hn = (t > 0) ? prev[sidx] : 0.f;
        sgv = fminf(fmaxf((presg + 1.f) * 0.5f, 0.f), 1.f);
    }
    cur[sidx] = hn;
    hist[((size_t)(t * 4 + k) * BB + b) * HH + j] = f2bf_rne(hn);

    float s = sgv;
#pragma unroll
    for (int off = 32; off > 0; off >>= 1) s += __shfl_down(s, off);
    if ((tid & 63) == 0) atomicAdd(&sgsum[t * 4 + k], s);
}

__global__ __launch_bounds__(256) void gates_kernel(
    const void* xin, const void* Um, const void* Jm, const void* bbias,
    const void* bnd, float* ws, int tau) {
    __shared__ float xs[BB][GG + 1];
    int mode = ((const int*)ws)[0];
    if (mode) gates_body<true>(xin, Um, Jm, bbias, bnd, ws, xs, tau);
    else      gates_body<false>(xin, Um, Jm, bbias, bnd, ws, xs, tau);
}

// ---- excitation epilogue ---------------------------------------------------
template <bool BF>
__device__ void excite_body(const float* ws, float* smem, const void* Qm,
                            const void* Rm, const void* Wom, const void* bom,
                            void* out) {
    float (*sh_hcat)[LL * HH] = (float(*)[LL * HH])smem;
    float (*sh_r)[HH] = (float(*)[HH])(smem + TT * LL * HH);
    const u16* hhist = (const u16*)(ws + HIST_OFF);
    int tid = threadIdx.x;
    int b = blockIdx.x >> 5;
    int t0 = (blockIdx.x & 31) * TT;

    for (int idx = tid; idx < TT * LL * HH; idx += 256) {
        int tt = idx / (LL * HH);
        int f = idx % (LL * HH);
        int kk = f / HH, j = f % HH;
        sh_hcat[tt][f] = bf2f(hhist[(((size_t)(t0 + tt) * LL + kk) * BB + b) * HH + j]);
    }
    __syncthreads();

    int h0 = tid * 2;
    float acc0[TT] = {0, 0, 0, 0}, acc1[TT] = {0, 0, 0, 0};
    for (int kk = 0; kk < LL; ++kk) {
        float r0[TT] = {0, 0, 0, 0}, r1[TT] = {0, 0, 0, 0};
        if (BF) {
            const u32* qp = (const u32*)((const u16*)Qm + (size_t)kk * (LL * HH) * HH) + tid;
#pragma unroll 4
            for (int f = 0; f < LL * HH; ++f) {
                float2 qv = bf2x2(qp[(size_t)f * 256]);
#pragma unroll
                for (int tt = 0; tt < TT; ++tt) {
                    float hc = sh_hcat[tt][f];
                    r0[tt] += qv.x * hc;
                    r1[tt] += qv.y * hc;
                }
            }
        } else {
            const float2* qp = (const float2*)((const float*)Qm + (size_t)kk * (LL * HH) * HH) + tid;
#pragma unroll 4
            for (int f = 0; f < LL * HH; ++f) {
                float2 qv = qp[(size_t)f * 256];
#pragma unroll
                for (int tt = 0; tt < TT; ++tt) {
                    float hc = sh_hcat[tt][f];
                    r0[tt] += qv.x * hc;
                    r1[tt] += qv.y * hc;
                }
            }
        }
        __syncthreads();
#pragma unroll
        for (int tt = 0; tt < TT; ++tt) {
            sh_r[tt][h0]     = 1.f / (1.f + expf(-r0[tt]));
            sh_r[tt][h0 + 1] = 1.f / (1.f + expf(-r1[tt]));
        }
        __syncthreads();
        float m0[TT] = {0, 0, 0, 0}, m1v[TT] = {0, 0, 0, 0};
        if (BF) {
            const u32* rp = (const u32*)((const u16*)Rm + (size_t)kk * HH * HH) + tid;
#pragma unroll 4
            for (int hh2 = 0; hh2 < HH; ++hh2) {
                float2 rv = bf2x2(rp[(size_t)hh2 * 256]);
#pragma unroll
                for (int tt = 0; tt < TT; ++tt) {
                    float rr = sh_r[tt][hh2];
                    m0[tt] += rv.x * rr;
                    m1v[tt] += rv.y * rr;
                }
            }
        } else {
            const float2* rp = (const float2*)((const float*)Rm + (size_t)kk * HH * HH) + tid;
#pragma unroll 4
            for (int hh2 = 0; hh2 < HH; ++hh2) {
                float2 rv = rp[(size_t)hh2 * 256];
#pragma unroll
                for (int tt = 0; tt < TT; ++tt) {
                    float rr = sh_r[tt][hh2];
                    m0[tt] += rv.x * rr;
                    m1v[tt] += rv.y * rr;
                }
            }
        }
#pragma unroll
        for (int tt = 0; tt < TT; ++tt) {
            acc0[tt] += m0[tt] * sh_hcat[tt][kk * HH + h0];
            acc1[tt] += m1v[tt] * sh_hcat[tt][kk * HH + h0 + 1];
        }
    }
    __syncthreads();
#pragma unroll
    for (int tt = 0; tt < TT; ++tt) {
        sh_r[tt][h0]     = fmaxf(acc0[tt], 0.f);
        sh_r[tt][h0 + 1] = fmaxf(acc1[tt], 0.f);
    }
    __syncthreads();
    {
        int tt = tid >> 6, f = tid & 63;
        float acc = 0.f;
        if (BF) {
            const uint4* wp = (const uint4*)((const u16*)Wom + (size_t)f * HH);
            const float4* ev = (const float4*)sh_r[tt];
#pragma unroll 8
            for (int it = 0; it < HH / 8; ++it) {
                uint4 qv = wp[it];
                float4 e0 = ev[2 * it], e1 = ev[2 * it + 1];
                float2 a0 = bf2x2(qv.x), a1 = bf2x2(qv.y), a2 = bf2x2(qv.z), a3 = bf2x2(qv.w);
                acc += a0.x * e0.x + a0.y * e0.y + a1.x * e0.z + a1.y * e0.w +
                       a2.x * e1.x + a2.y * e1.y + a3.x * e1.z + a3.y * e1.w;
            }
        } else {
            const float4* wp = (const float4*)((const float*)Wom + (size_t)f * HH);
            const float4* ev = (const float4*)sh_r[tt];
#pragma unroll 8
            for (int it = 0; it < HH / 4; ++it) {
                float4 qv = wp[it], e = ev[it];
                acc += qv.x * e.x + qv.y * e.y + qv.z * e.z + qv.w * e.w;
            }
        }
        acc += ldv<BF>(bom, f);
        size_t oidx = ((size_t)b * TS + (t0 + tt)) * FF + f;
        if (BF) ((u16*)out)[oidx] = f2bf_rne(acc);
        else    ((float*)out)[oidx] = acc;
    }
}

__global__ __launch_bounds__(256) void excite_kernel(
    const float* ws, const void* Qm, const void* Rm, const void* Wom,
    const void* bom, void* out) {
    extern __shared__ float smem[];
    int mode = ((const int*)ws)[0];
    if (mode) excite_body<true>(ws, smem, Qm, Rm, Wom, bom, out);
    else      excite_body<false>(ws, smem, Qm, Rm, Wom, bom, out);
}

extern "C" void kernel_launch(void* const* d_in, const int* in_sizes, int n_in,
                              void* d_out, int out_size, void* d_ws, size_t ws_size,
                              hipStream_t stream) {
    const void* xin = d_in[0];
    const void* Wm  = d_in[1];
    const void* Zm  = d_in[2];
    const void* Um  = d_in[3];
    const void* Vm  = d_in[4];
    const void* Jm  = d_in[5];
    const void* bb  = d_in[6];
    const void* bnd = d_in[7];
    const void* Qm  = d_in[8];
    const void* Rm  = d_in[9];
    const void* Wo  = d_in[10];
    const void* bo  = d_in[11];
    float* ws = (float*)d_ws;

    initA_kernel<<<dim3(512), dim3(256), 0, stream>>>((const u16*)bnd, ws);
    initB_kernel<<<dim3(512), dim3(64), 0, stream>>>(xin, ws);
    for (int tau = 0; tau <= 2 * (TS - 1) + (LL - 1); ++tau) {   // 258 phases
        gemm_kernel<<<dim3(768), dim3(256), 0, stream>>>(Wm, Zm, Um, Vm, bnd, ws, tau);
        gates_kernel<<<dim3(256), dim3(256), 0, stream>>>(xin, Um, Jm, bb, bnd, ws, tau);
    }
    size_t exc_smem = (TT * LL * HH + TT * HH) * sizeof(float);  // 40 KB
    excite_kernel<<<dim3(2048), dim3(256), exc_smem, stream>>>(
        ws, Qm, Rm, Wo, bo, d_out);
}